// Round 1
// baseline (313.459 us; speedup 1.0000x reference)
//
#include <hip/hip_runtime.h>

#define NC 8192
#define CC 2048
#define EPS 1e-5f

__device__ __forceinline__ unsigned short f2bf(float f) {
  unsigned int u = __float_as_uint(f);
  u += 0x7FFFu + ((u >> 16) & 1u);
  return (unsigned short)(u >> 16);
}
__device__ __forceinline__ float bf2f(unsigned short s) {
  return __uint_as_float(((unsigned int)s) << 16);
}

__global__ __launch_bounds__(256, 4)
void lora_fused(const float* __restrict__ x,
                const float* __restrict__ outp,
                const float* __restrict__ wnorm,
                const float* __restrict__ phi_pre,
                const float* __restrict__ phi_post,
                const float* __restrict__ phi_res,
                const float* __restrict__ b_pre,
                const float* __restrict__ b_post,
                const float* __restrict__ b_res,
                const float* __restrict__ a_pre,
                const float* __restrict__ a_post,
                const float* __restrict__ a_res,
                const int* __restrict__ aidx_arr,
                float* __restrict__ agg_out,
                float* __restrict__ big_out) {
  __shared__ unsigned short xs[2][NC];      // bf16 copy of the 2 token rows
  __shared__ float scratch[4][52];
  __shared__ float red[52];
  __shared__ float Hpre[2][4], Hpost[2][4], Msm[2][16];

  const int tid  = threadIdx.x;
  const int g    = blockIdx.x;
  const int tok0 = g * 2;
  const int b    = tok0 >> 10;              // T = 1024
  const int aidx = aidx_arr[b];

  const float* xr0 = x + (size_t)tok0 * NC;
  const float* xr1 = xr0 + NC;
  const float* wr  = wnorm    + (size_t)aidx * NC;
  const float* pp  = phi_pre  + (size_t)aidx * NC * 4;
  const float* pq  = phi_post + (size_t)aidx * NC * 4;
  const float* pr  = phi_res  + (size_t)aidx * NC * 16;

  // acc[t*25 + 0] = sumsq(token t); acc[t*25 + 1 + c] = dot c (0-3 pre, 4-7 post, 8-23 res)
  float acc[50];
  #pragma unroll
  for (int i = 0; i < 50; ++i) acc[i] = 0.f;

  for (int k = 0; k < 8; ++k) {
    const int f0 = (k * 256 + tid) * 4;
    const float4 w4 = *(const float4*)(wr  + f0);
    const float4 xa = *(const float4*)(xr0 + f0);
    const float4 xb = *(const float4*)(xr1 + f0);

    acc[0]  += xa.x*xa.x + xa.y*xa.y + xa.z*xa.z + xa.w*xa.w;
    acc[25] += xb.x*xb.x + xb.y*xb.y + xb.z*xb.z + xb.w*xb.w;

    float xw0[4] = { xa.x*w4.x, xa.y*w4.y, xa.z*w4.z, xa.w*w4.w };
    float xw1[4] = { xb.x*w4.x, xb.y*w4.y, xb.z*w4.z, xb.w*w4.w };

    *(ushort4*)&xs[0][f0] = make_ushort4(f2bf(xa.x), f2bf(xa.y), f2bf(xa.z), f2bf(xa.w));
    *(ushort4*)&xs[1][f0] = make_ushort4(f2bf(xb.x), f2bf(xb.y), f2bf(xb.z), f2bf(xb.w));

    #pragma unroll
    for (int d = 0; d < 4; ++d) {
      const int f = f0 + d;
      const float a0 = xw0[d], a1 = xw1[d];
      float col[24];
      const float4 P  = *(const float4*)(pp + ((size_t)f << 2));
      const float4 Q  = *(const float4*)(pq + ((size_t)f << 2));
      const float4 R0 = *(const float4*)(pr + ((size_t)f << 4));
      const float4 R1 = *(const float4*)(pr + ((size_t)f << 4) + 4);
      const float4 R2 = *(const float4*)(pr + ((size_t)f << 4) + 8);
      const float4 R3 = *(const float4*)(pr + ((size_t)f << 4) + 12);
      col[0]=P.x;  col[1]=P.y;  col[2]=P.z;  col[3]=P.w;
      col[4]=Q.x;  col[5]=Q.y;  col[6]=Q.z;  col[7]=Q.w;
      col[8]=R0.x; col[9]=R0.y; col[10]=R0.z; col[11]=R0.w;
      col[12]=R1.x; col[13]=R1.y; col[14]=R1.z; col[15]=R1.w;
      col[16]=R2.x; col[17]=R2.y; col[18]=R2.z; col[19]=R2.w;
      col[20]=R3.x; col[21]=R3.y; col[22]=R3.z; col[23]=R3.w;
      #pragma unroll
      for (int c = 0; c < 24; ++c) {
        acc[1 + c]  += a0 * col[c];
        acc[26 + c] += a1 * col[c];
      }
    }
  }

  // block reduction of 50 partials: butterfly within wave, then cross-wave via LDS
  #pragma unroll
  for (int m = 1; m <= 32; m <<= 1) {
    #pragma unroll
    for (int v = 0; v < 50; ++v) acc[v] += __shfl_xor(acc[v], m, 64);
  }
  const int wave = tid >> 6, lane = tid & 63;
  if (lane == 0) {
    #pragma unroll
    for (int v = 0; v < 50; ++v) scratch[wave][v] = acc[v];
  }
  __syncthreads();
  if (tid < 50) {
    red[tid] = scratch[0][tid] + scratch[1][tid] + scratch[2][tid] + scratch[3][tid];
  }
  __syncthreads();

  if (tid < 32) {
    // Sinkhorn: lanes 0-15 token 0, lanes 16-31 token 1; l = i*4 + j
    const int t = tid >> 4, l = tid & 15;
    const float invr = rsqrtf(red[t * 25] * (1.f / NC) + EPS);
    const float ar = a_res[aidx];
    const float tl = ar * red[t * 25 + 1 + 8 + l] * invr + b_res[(size_t)aidx * 16 + l];
    float m = __expf(tl);
    #pragma unroll
    for (int it = 0; it < 20; ++it) {
      float rs = m;
      rs += __shfl_xor(rs, 1, 64);
      rs += __shfl_xor(rs, 2, 64);
      m *= __builtin_amdgcn_rcpf(rs);
      float cs = m;
      cs += __shfl_xor(cs, 4, 64);
      cs += __shfl_xor(cs, 8, 64);
      m *= __builtin_amdgcn_rcpf(cs);
    }
    Msm[t][l] = m;
  } else if (tid < 40) {
    const int q = tid - 32;
    const int t = q >> 2, n = q & 3;
    const float invr = rsqrtf(red[t * 25] * (1.f / NC) + EPS);
    const float zp = a_pre[aidx]  * red[t * 25 + 1 + n]     * invr + b_pre[(size_t)aidx * 4 + n];
    const float zq = a_post[aidx] * red[t * 25 + 1 + 4 + n] * invr + b_post[(size_t)aidx * 4 + n];
    Hpre[t][n]  = 1.f / (1.f + __expf(-zp));
    Hpost[t][n] = 2.f / (1.f + __expf(-zq));
  }
  __syncthreads();

  // output pass
  #pragma unroll
  for (int t = 0; t < 2; ++t) {
    const int tok = tok0 + t;
    const float* orow = outp    + (size_t)tok * CC;
    float* arow       = agg_out + (size_t)tok * CC;
    float* brow       = big_out + (size_t)tok * 4 * CC;
    const float hp0 = Hpre[t][0], hp1 = Hpre[t][1], hp2 = Hpre[t][2], hp3 = Hpre[t][3];
    float Mr[16];
    #pragma unroll
    for (int i = 0; i < 16; ++i) Mr[i] = Msm[t][i];
    const float hq0 = Hpost[t][0], hq1 = Hpost[t][1], hq2 = Hpost[t][2], hq3 = Hpost[t][3];

    #pragma unroll
    for (int w = 0; w < 2; ++w) {
      const int c0 = (w * 256 + tid) * 4;
      float4 xv[4];
      #pragma unroll
      for (int n = 0; n < 4; ++n) {
        const ushort4 u = *(const ushort4*)&xs[t][n * CC + c0];
        xv[n] = make_float4(bf2f(u.x), bf2f(u.y), bf2f(u.z), bf2f(u.w));
      }
      const float4 ov = *(const float4*)(orow + c0);

      float4 ag;
      ag.x = hp0*xv[0].x + hp1*xv[1].x + hp2*xv[2].x + hp3*xv[3].x;
      ag.y = hp0*xv[0].y + hp1*xv[1].y + hp2*xv[2].y + hp3*xv[3].y;
      ag.z = hp0*xv[0].z + hp1*xv[1].z + hp2*xv[2].z + hp3*xv[3].z;
      ag.w = hp0*xv[0].w + hp1*xv[1].w + hp2*xv[2].w + hp3*xv[3].w;
      *(float4*)(arow + c0) = ag;

      const float hq[4] = { hq0, hq1, hq2, hq3 };
      #pragma unroll
      for (int i = 0; i < 4; ++i) {
        const float m0 = Mr[i*4+0], m1 = Mr[i*4+1], m2 = Mr[i*4+2], m3 = Mr[i*4+3];
        float4 o;
        o.x = m0*xv[0].x + m1*xv[1].x + m2*xv[2].x + m3*xv[3].x + hq[i]*ov.x;
        o.y = m0*xv[0].y + m1*xv[1].y + m2*xv[2].y + m3*xv[3].y + hq[i]*ov.y;
        o.z = m0*xv[0].z + m1*xv[1].z + m2*xv[2].z + m3*xv[3].z + hq[i]*ov.z;
        o.w = m0*xv[0].w + m1*xv[1].w + m2*xv[2].w + m3*xv[3].w + hq[i]*ov.w;
        *(float4*)(brow + (size_t)i * CC + c0) = o;
      }
    }
  }
}

extern "C" void kernel_launch(void* const* d_in, const int* in_sizes, int n_in,
                              void* d_out, int out_size, void* d_ws, size_t ws_size,
                              hipStream_t stream) {
  const float* x     = (const float*)d_in[0];
  const float* outp  = (const float*)d_in[1];
  const float* wnorm = (const float*)d_in[2];
  const float* ppre  = (const float*)d_in[3];
  const float* ppost = (const float*)d_in[4];
  const float* pres  = (const float*)d_in[5];
  const float* bpre  = (const float*)d_in[6];
  const float* bpost = (const float*)d_in[7];
  const float* bres  = (const float*)d_in[8];
  const float* apre  = (const float*)d_in[9];
  const float* apost = (const float*)d_in[10];
  const float* ares  = (const float*)d_in[11];
  const int*   aidx  = (const int*)d_in[12];

  float* agg = (float*)d_out;                                  // (B,T,C)
  float* big = (float*)d_out + (size_t)4 * 1024 * 2048;        // (B,T,N,C)

  dim3 grid(2048), block(256);
  hipLaunchKernelGGL(lora_fused, grid, block, 0, stream,
                     x, outp, wnorm, ppre, ppost, pres,
                     bpre, bpost, bres, apre, apost, ares,
                     aidx, agg, big);
}

// Round 2
// 115.466 us; speedup vs baseline: 2.7147x; 2.7147x over previous
//
#include <hip/hip_runtime.h>

#define EPS 1e-5f
#define TOKS 4096
#define NCF 8192
#define CCH 2048
#define PHI_T_BYTES ((size_t)8 * 32 * 8192 * 2)          // 4 MB bf16 phiT
#define GATES_OFF PHI_T_BYTES
#define WS_NEED (PHI_T_BYTES + (size_t)TOKS * 32 * 4)

typedef __attribute__((ext_vector_type(8))) short bf16x8;
typedef __attribute__((ext_vector_type(4))) float f32x4;

__device__ __forceinline__ unsigned short f2bf(float f) {
  unsigned int u = __float_as_uint(f);
  u += 0x7FFFu + ((u >> 16) & 1u);
  return (unsigned short)(u >> 16);
}
__device__ __forceinline__ float bf2f(unsigned short s) {
  return __uint_as_float(((unsigned int)s) << 16);
}

// ---------------- K0: phi (f32, [A][f][n]) -> phiT (bf16, [A][32 rows][8192]) ----------------
// rows 0-3 = pre cols, 4-7 = post cols, 8-23 = res cols, 24-31 = zero
__global__ __launch_bounds__(256)
void prep_phiT(const float* __restrict__ pre, const float* __restrict__ post,
               const float* __restrict__ res, unsigned short* __restrict__ phiT) {
  const int gid = blockIdx.x * 256 + threadIdx.x;   // 8*32*1024
  const int a = gid >> 15;
  const int r = (gid >> 10) & 31;
  const int f = (gid & 1023) * 8;
  unsigned int w[4];
  #pragma unroll
  for (int p = 0; p < 4; ++p) {
    float v0 = 0.f, v1 = 0.f;
    const int e0 = f + 2 * p, e1 = f + 2 * p + 1;
    if (r < 4) {
      v0 = pre[((size_t)a * NCF + e0) * 4 + r];
      v1 = pre[((size_t)a * NCF + e1) * 4 + r];
    } else if (r < 8) {
      v0 = post[((size_t)a * NCF + e0) * 4 + (r - 4)];
      v1 = post[((size_t)a * NCF + e1) * 4 + (r - 4)];
    } else if (r < 24) {
      v0 = res[((size_t)a * NCF + e0) * 16 + (r - 8)];
      v1 = res[((size_t)a * NCF + e1) * 16 + (r - 8)];
    }
    w[p] = (unsigned int)f2bf(v0) | ((unsigned int)f2bf(v1) << 16);
  }
  *(uint4*)(phiT + ((size_t)a * 32 + r) * NCF + f) = make_uint4(w[0], w[1], w[2], w[3]);
}

// ---------------- K1: logits via MFMA + rms + sigmoid + Sinkhorn -> gates[tok][32] ----------------
__global__ __launch_bounds__(256, 1)
void logits_gates(const float* __restrict__ x,
                  const float* __restrict__ wnorm,
                  const unsigned short* __restrict__ phiT,
                  const float* __restrict__ b_pre, const float* __restrict__ b_post,
                  const float* __restrict__ b_res,
                  const float* __restrict__ a_pre, const float* __restrict__ a_post,
                  const float* __restrict__ a_res,
                  const int* __restrict__ aidx_arr,
                  float* __restrict__ gates) {
  __shared__ unsigned short xs[4][16 * 264];   // per-wave bf16 tile [16 tok][256 feat], row pad 264
  __shared__ float logits_s[4][16][32];
  __shared__ float ssq_s[4][16];

  const int tid = threadIdx.x;
  const int wave = tid >> 6, lane = tid & 63;
  const int tok0 = blockIdx.x * 16;
  const int aidx = aidx_arr[tok0 >> 10];
  const int kbase = wave * 2048;

  const float* xbase = x + (size_t)tok0 * NCF + kbase + (lane & 63) * 4;
  const float* wbase = wnorm + (size_t)aidx * NCF + kbase + lane * 4;
  const unsigned short* pBbase =
      phiT + ((size_t)aidx * 32 + (lane & 15)) * NCF + kbase + (lane >> 4) * 8;

  f32x4 acc0 = {0.f, 0.f, 0.f, 0.f};
  f32x4 acc1 = {0.f, 0.f, 0.f, 0.f};
  float ssq[16];
  #pragma unroll
  for (int r = 0; r < 16; ++r) ssq[r] = 0.f;

  float4 xr[16];
  #pragma unroll
  for (int r = 0; r < 16; ++r) xr[r] = *(const float4*)(xbase + (size_t)r * NCF);

  for (int t = 0; t < 8; ++t) {
    const float4 wv = *(const float4*)(wbase + t * 256);
    // stage: ssq + bf16(w*x) -> LDS (wave-private, no barrier needed)
    #pragma unroll
    for (int r = 0; r < 16; ++r) {
      const float4 xv = xr[r];
      ssq[r] += xv.x * xv.x + xv.y * xv.y + xv.z * xv.z + xv.w * xv.w;
      ushort4 u = make_ushort4(f2bf(xv.x * wv.x), f2bf(xv.y * wv.y),
                               f2bf(xv.z * wv.z), f2bf(xv.w * wv.w));
      *(ushort4*)&xs[wave][r * 264 + lane * 4] = u;
    }
    if (t < 7) {
      #pragma unroll
      for (int r = 0; r < 16; ++r)
        xr[r] = *(const float4*)(xbase + (size_t)r * NCF + (t + 1) * 256);
    }
    const unsigned short* pB = pBbase + t * 256;
    #pragma unroll
    for (int s = 0; s < 8; ++s) {
      bf16x8 a = *(const bf16x8*)&xs[wave][(lane & 15) * 264 + s * 32 + (lane >> 4) * 8];
      bf16x8 b0 = *(const bf16x8*)(pB + s * 32);
      bf16x8 b1 = *(const bf16x8*)(pB + 16 * NCF + s * 32);
      acc0 = __builtin_amdgcn_mfma_f32_16x16x32_bf16(a, b0, acc0, 0, 0, 0);
      acc1 = __builtin_amdgcn_mfma_f32_16x16x32_bf16(a, b1, acc1, 0, 0, 0);
    }
  }

  // ssq reduce across 64 lanes
  #pragma unroll
  for (int r = 0; r < 16; ++r) {
    float v = ssq[r];
    #pragma unroll
    for (int m = 1; m <= 32; m <<= 1) v += __shfl_xor(v, m, 64);
    if (lane == 0) ssq_s[wave][r] = v;
  }
  // C frags -> LDS: D[m=tok][n=col], m=(lane>>4)*4+i, n=lane&15
  #pragma unroll
  for (int i = 0; i < 4; ++i) {
    logits_s[wave][(lane >> 4) * 4 + i][lane & 15] = acc0[i];
    logits_s[wave][(lane >> 4) * 4 + i][16 + (lane & 15)] = acc1[i];
  }
  __syncthreads();

  // per-thread: tok = tid>>4 (0..15), cl = tid&15
  const int tok = tid >> 4, cl = tid & 15;
  float L0 = logits_s[0][tok][cl] + logits_s[1][tok][cl] +
             logits_s[2][tok][cl] + logits_s[3][tok][cl];
  float L16 = logits_s[0][tok][16 + cl] + logits_s[1][tok][16 + cl] +
              logits_s[2][tok][16 + cl] + logits_s[3][tok][16 + cl];
  const float ssqt = ssq_s[0][tok] + ssq_s[1][tok] + ssq_s[2][tok] + ssq_s[3][tok];
  const float invr = rsqrtf(ssqt * (1.f / NCF) + EPS);

  float* g = gates + (size_t)(tok0 + tok) * 32;
  if (cl < 4) {
    const float zp = a_pre[aidx] * L0 * invr + b_pre[(size_t)aidx * 4 + cl];
    g[cl] = 1.f / (1.f + __expf(-zp));
  } else if (cl < 8) {
    const float zq = a_post[aidx] * L0 * invr + b_post[(size_t)aidx * 4 + (cl - 4)];
    g[cl] = 2.f / (1.f + __expf(-zq));
  }
  // gather res logits: res[cl] = col 8+cl
  const float resv = __shfl_xor((cl & 8) ? L0 : L16, 8, 64);
  const float tl = a_res[aidx] * resv * invr + b_res[(size_t)aidx * 16 + cl];
  float m = __expf(tl);
  #pragma unroll
  for (int it = 0; it < 20; ++it) {
    float rs = m;
    rs += __shfl_xor(rs, 1, 64);
    rs += __shfl_xor(rs, 2, 64);
    m *= __builtin_amdgcn_rcpf(rs);
    float cs = m;
    cs += __shfl_xor(cs, 4, 64);
    cs += __shfl_xor(cs, 8, 64);
    m *= __builtin_amdgcn_rcpf(cs);
  }
  g[8 + cl] = m;
}

// ---------------- K3: streaming output pass ----------------
__global__ __launch_bounds__(256)
void out_pass(const float* __restrict__ x, const float* __restrict__ outp,
              const float* __restrict__ gates,
              float* __restrict__ agg, float* __restrict__ big) {
  const int tok = blockIdx.x;
  const int tid = threadIdx.x;
  const float* g = gates + (size_t)tok * 32;
  float hp[4], hq[4], M[16];
  #pragma unroll
  for (int i = 0; i < 4; ++i) { hp[i] = g[i]; hq[i] = g[4 + i]; }
  #pragma unroll
  for (int i = 0; i < 16; ++i) M[i] = g[8 + i];

  const float* xrow = x + (size_t)tok * NCF;
  const float* orow = outp + (size_t)tok * CCH;
  float* arow = agg + (size_t)tok * CCH;
  float* brow = big + (size_t)tok * NCF;

  #pragma unroll
  for (int rep = 0; rep < 2; ++rep) {
    const int c = rep * 1024 + tid * 4;
    float4 xv[4];
    #pragma unroll
    for (int j = 0; j < 4; ++j) xv[j] = *(const float4*)(xrow + j * CCH + c);
    const float4 ov = *(const float4*)(orow + c);

    float4 ag;
    ag.x = hp[0]*xv[0].x + hp[1]*xv[1].x + hp[2]*xv[2].x + hp[3]*xv[3].x;
    ag.y = hp[0]*xv[0].y + hp[1]*xv[1].y + hp[2]*xv[2].y + hp[3]*xv[3].y;
    ag.z = hp[0]*xv[0].z + hp[1]*xv[1].z + hp[2]*xv[2].z + hp[3]*xv[3].z;
    ag.w = hp[0]*xv[0].w + hp[1]*xv[1].w + hp[2]*xv[2].w + hp[3]*xv[3].w;
    *(float4*)(arow + c) = ag;

    #pragma unroll
    for (int i = 0; i < 4; ++i) {
      const float m0 = M[i*4+0], m1 = M[i*4+1], m2 = M[i*4+2], m3 = M[i*4+3];
      float4 o;
      o.x = m0*xv[0].x + m1*xv[1].x + m2*xv[2].x + m3*xv[3].x + hq[i]*ov.x;
      o.y = m0*xv[0].y + m1*xv[1].y + m2*xv[2].y + m3*xv[3].y + hq[i]*ov.y;
      o.z = m0*xv[0].z + m1*xv[1].z + m2*xv[2].z + m3*xv[3].z + hq[i]*ov.z;
      o.w = m0*xv[0].w + m1*xv[1].w + m2*xv[2].w + m3*xv[3].w + hq[i]*ov.w;
      *(float4*)(brow + i * CCH + c) = o;
    }
  }
}

// ---------------- fallback: round-1 fused kernel (used if ws too small) ----------------
__global__ __launch_bounds__(256, 4)
void lora_fused(const float* __restrict__ x, const float* __restrict__ outp,
                const float* __restrict__ wnorm, const float* __restrict__ phi_pre,
                const float* __restrict__ phi_post, const float* __restrict__ phi_res,
                const float* __restrict__ b_pre, const float* __restrict__ b_post,
                const float* __restrict__ b_res, const float* __restrict__ a_pre,
                const float* __restrict__ a_post, const float* __restrict__ a_res,
                const int* __restrict__ aidx_arr, float* __restrict__ agg_out,
                float* __restrict__ big_out) {
  __shared__ unsigned short xsb[2][NCF];
  __shared__ float scratch[4][52];
  __shared__ float red[52];
  __shared__ float Hpre[2][4], Hpost[2][4], Msm[2][16];
  const int tid = threadIdx.x;
  const int tok0 = blockIdx.x * 2;
  const int aidx = aidx_arr[tok0 >> 10];
  const float* xr0 = x + (size_t)tok0 * NCF;
  const float* xr1 = xr0 + NCF;
  const float* wr = wnorm + (size_t)aidx * NCF;
  const float* pp = phi_pre + (size_t)aidx * NCF * 4;
  const float* pq = phi_post + (size_t)aidx * NCF * 4;
  const float* pr = phi_res + (size_t)aidx * NCF * 16;
  float acc[50];
  #pragma unroll
  for (int i = 0; i < 50; ++i) acc[i] = 0.f;
  for (int k = 0; k < 8; ++k) {
    const int f0 = (k * 256 + tid) * 4;
    const float4 w4 = *(const float4*)(wr + f0);
    const float4 xa = *(const float4*)(xr0 + f0);
    const float4 xb = *(const float4*)(xr1 + f0);
    acc[0] += xa.x*xa.x + xa.y*xa.y + xa.z*xa.z + xa.w*xa.w;
    acc[25] += xb.x*xb.x + xb.y*xb.y + xb.z*xb.z + xb.w*xb.w;
    float xw0[4] = { xa.x*w4.x, xa.y*w4.y, xa.z*w4.z, xa.w*w4.w };
    float xw1[4] = { xb.x*w4.x, xb.y*w4.y, xb.z*w4.z, xb.w*w4.w };
    *(ushort4*)&xsb[0][f0] = make_ushort4(f2bf(xa.x), f2bf(xa.y), f2bf(xa.z), f2bf(xa.w));
    *(ushort4*)&xsb[1][f0] = make_ushort4(f2bf(xb.x), f2bf(xb.y), f2bf(xb.z), f2bf(xb.w));
    #pragma unroll
    for (int d = 0; d < 4; ++d) {
      const int f = f0 + d;
      const float a0 = xw0[d], a1 = xw1[d];
      float col[24];
      const float4 P = *(const float4*)(pp + ((size_t)f << 2));
      const float4 Q = *(const float4*)(pq + ((size_t)f << 2));
      const float4 R0 = *(const float4*)(pr + ((size_t)f << 4));
      const float4 R1 = *(const float4*)(pr + ((size_t)f << 4) + 4);
      const float4 R2 = *(const float4*)(pr + ((size_t)f << 4) + 8);
      const float4 R3 = *(const float4*)(pr + ((size_t)f << 4) + 12);
      col[0]=P.x; col[1]=P.y; col[2]=P.z; col[3]=P.w;
      col[4]=Q.x; col[5]=Q.y; col[6]=Q.z; col[7]=Q.w;
      col[8]=R0.x; col[9]=R0.y; col[10]=R0.z; col[11]=R0.w;
      col[12]=R1.x; col[13]=R1.y; col[14]=R1.z; col[15]=R1.w;
      col[16]=R2.x; col[17]=R2.y; col[18]=R2.z; col[19]=R2.w;
      col[20]=R3.x; col[21]=R3.y; col[22]=R3.z; col[23]=R3.w;
      #pragma unroll
      for (int c = 0; c < 24; ++c) { acc[1 + c] += a0 * col[c]; acc[26 + c] += a1 * col[c]; }
    }
  }
  #pragma unroll
  for (int m = 1; m <= 32; m <<= 1) {
    #pragma unroll
    for (int v = 0; v < 50; ++v) acc[v] += __shfl_xor(acc[v], m, 64);
  }
  const int wave = tid >> 6, lane = tid & 63;
  if (lane == 0) {
    #pragma unroll
    for (int v = 0; v < 50; ++v) scratch[wave][v] = acc[v];
  }
  __syncthreads();
  if (tid < 50) red[tid] = scratch[0][tid] + scratch[1][tid] + scratch[2][tid] + scratch[3][tid];
  __syncthreads();
  if (tid < 32) {
    const int t = tid >> 4, l = tid & 15;
    const float invr = rsqrtf(red[t * 25] * (1.f / NCF) + EPS);
    const float tl = a_res[aidx] * red[t * 25 + 1 + 8 + l] * invr + b_res[(size_t)aidx * 16 + l];
    float m = __expf(tl);
    #pragma unroll
    for (int it = 0; it < 20; ++it) {
      float rs = m; rs += __shfl_xor(rs, 1, 64); rs += __shfl_xor(rs, 2, 64);
      m *= __builtin_amdgcn_rcpf(rs);
      float cs = m; cs += __shfl_xor(cs, 4, 64); cs += __shfl_xor(cs, 8, 64);
      m *= __builtin_amdgcn_rcpf(cs);
    }
    Msm[t][l] = m;
  } else if (tid < 40) {
    const int q = tid - 32, t = q >> 2, n = q & 3;
    const float invr = rsqrtf(red[t * 25] * (1.f / NCF) + EPS);
    const float zp = a_pre[aidx] * red[t * 25 + 1 + n] * invr + b_pre[(size_t)aidx * 4 + n];
    const float zq = a_post[aidx] * red[t * 25 + 1 + 4 + n] * invr + b_post[(size_t)aidx * 4 + n];
    Hpre[t][n] = 1.f / (1.f + __expf(-zp));
    Hpost[t][n] = 2.f / (1.f + __expf(-zq));
  }
  __syncthreads();
  #pragma unroll
  for (int t = 0; t < 2; ++t) {
    const int tok = tok0 + t;
    const float* orow = outp + (size_t)tok * CCH;
    float* arow = agg_out + (size_t)tok * CCH;
    float* brow = big_out + (size_t)tok * 4 * CCH;
    const float hp0 = Hpre[t][0], hp1 = Hpre[t][1], hp2 = Hpre[t][2], hp3 = Hpre[t][3];
    float Mr[16];
    #pragma unroll
    for (int i = 0; i < 16; ++i) Mr[i] = Msm[t][i];
    const float hq[4] = { Hpost[t][0], Hpost[t][1], Hpost[t][2], Hpost[t][3] };
    #pragma unroll
    for (int w = 0; w < 2; ++w) {
      const int c0 = (w * 256 + tid) * 4;
      float4 xv[4];
      #pragma unroll
      for (int n = 0; n < 4; ++n) {
        const ushort4 u = *(const ushort4*)&xsb[t][n * CCH + c0];
        xv[n] = make_float4(bf2f(u.x), bf2f(u.y), bf2f(u.z), bf2f(u.w));
      }
      const float4 ov = *(const float4*)(orow + c0);
      float4 ag;
      ag.x = hp0*xv[0].x + hp1*xv[1].x + hp2*xv[2].x + hp3*xv[3].x;
      ag.y = hp0*xv[0].y + hp1*xv[1].y + hp2*xv[2].y + hp3*xv[3].y;
      ag.z = hp0*xv[0].z + hp1*xv[1].z + hp2*xv[2].z + hp3*xv[3].z;
      ag.w = hp0*xv[0].w + hp1*xv[1].w + hp2*xv[2].w + hp3*xv[3].w;
      *(float4*)(arow + c0) = ag;
      #pragma unroll
      for (int i = 0; i < 4; ++i) {
        const float m0 = Mr[i*4+0], m1 = Mr[i*4+1], m2 = Mr[i*4+2], m3 = Mr[i*4+3];
        float4 o;
        o.x = m0*xv[0].x + m1*xv[1].x + m2*xv[2].x + m3*xv[3].x + hq[i]*ov.x;
        o.y = m0*xv[0].y + m1*xv[1].y + m2*xv[2].y + m3*xv[3].y + hq[i]*ov.y;
        o.z = m0*xv[0].z + m1*xv[1].z + m2*xv[2].z + m3*xv[3].z + hq[i]*ov.z;
        o.w = m0*xv[0].w + m1*xv[1].w + m2*xv[2].w + m3*xv[3].w + hq[i]*ov.w;
        *(float4*)(brow + (size_t)i * CCH + c0) = o;
      }
    }
  }
}

extern "C" void kernel_launch(void* const* d_in, const int* in_sizes, int n_in,
                              void* d_out, int out_size, void* d_ws, size_t ws_size,
                              hipStream_t stream) {
  const float* x     = (const float*)d_in[0];
  const float* outp  = (const float*)d_in[1];
  const float* wnorm = (const float*)d_in[2];
  const float* ppre  = (const float*)d_in[3];
  const float* ppost = (const float*)d_in[4];
  const float* pres  = (const float*)d_in[5];
  const float* bpre  = (const float*)d_in[6];
  const float* bpost = (const float*)d_in[7];
  const float* bres  = (const float*)d_in[8];
  const float* apre  = (const float*)d_in[9];
  const float* apost = (const float*)d_in[10];
  const float* ares  = (const float*)d_in[11];
  const int*   aidx  = (const int*)d_in[12];

  float* agg = (float*)d_out;
  float* big = (float*)d_out + (size_t)TOKS * CCH;

  if (ws_size >= WS_NEED) {
    unsigned short* phiT = (unsigned short*)d_ws;
    float* gates = (float*)((char*)d_ws + GATES_OFF);
    hipLaunchKernelGGL(prep_phiT, dim3(1024), dim3(256), 0, stream, ppre, ppost, pres, phiT);
    hipLaunchKernelGGL(logits_gates, dim3(256), dim3(256), 0, stream,
                       x, wnorm, phiT, bpre, bpost, bres, apre, apost, ares, aidx, gates);
    hipLaunchKernelGGL(out_pass, dim3(4096), dim3(256), 0, stream, x, outp, gates, agg, big);
  } else {
    hipLaunchKernelGGL(lora_fused, dim3(2048), dim3(256), 0, stream,
                       x, outp, wnorm, ppre, ppost, pres,
                       bpre, bpost, bres, apre, apost, ares, aidx, agg, big);
  }
}

// Round 6
// 100.747 us; speedup vs baseline: 3.1113x; 1.1461x over previous
//
#include <hip/hip_runtime.h>

#define EPS 1e-5f
#define TOKS 4096
#define NCF 8192
#define CCH 2048
#define PHI_T_BYTES ((size_t)8 * 32 * 8192 * 2)          // 4 MB bf16 phiT
#define GATES_OFF PHI_T_BYTES
#define WS_NEED (PHI_T_BYTES + (size_t)TOKS * 32 * 4)

typedef __attribute__((ext_vector_type(8))) short bf16x8;
typedef __attribute__((ext_vector_type(4))) float f32x4;

__device__ __forceinline__ unsigned short f2bf(float f) {
  unsigned int u = __float_as_uint(f);
  u += 0x7FFFu + ((u >> 16) & 1u);
  return (unsigned short)(u >> 16);
}
__device__ __forceinline__ float bf2f(unsigned short s) {
  return __uint_as_float(((unsigned int)s) << 16);
}

// ---------------- K0: phi (f32, [A][f][n]) -> phiT (bf16, [A][32 rows][8192]) ----------------
// rows 0-3 = pre cols, 4-7 = post cols, 8-23 = res cols, 24-31 = zero
__global__ __launch_bounds__(256)
void prep_phiT(const float* __restrict__ pre, const float* __restrict__ post,
               const float* __restrict__ res, unsigned short* __restrict__ phiT) {
  const int gid = blockIdx.x * 256 + threadIdx.x;   // 8*32*1024
  const int a = gid >> 15;
  const int r = (gid >> 10) & 31;
  const int f = (gid & 1023) * 8;
  unsigned int w[4];
  #pragma unroll
  for (int p = 0; p < 4; ++p) {
    float v0 = 0.f, v1 = 0.f;
    const int e0 = f + 2 * p, e1 = f + 2 * p + 1;
    if (r < 4) {
      v0 = pre[((size_t)a * NCF + e0) * 4 + r];
      v1 = pre[((size_t)a * NCF + e1) * 4 + r];
    } else if (r < 8) {
      v0 = post[((size_t)a * NCF + e0) * 4 + (r - 4)];
      v1 = post[((size_t)a * NCF + e1) * 4 + (r - 4)];
    } else if (r < 24) {
      v0 = res[((size_t)a * NCF + e0) * 16 + (r - 8)];
      v1 = res[((size_t)a * NCF + e1) * 16 + (r - 8)];
    }
    w[p] = (unsigned int)f2bf(v0) | ((unsigned int)f2bf(v1) << 16);
  }
  *(uint4*)(phiT + ((size_t)a * 32 + r) * NCF + f) = make_uint4(w[0], w[1], w[2], w[3]);
}

// ---------------- K1: logits via MFMA + rms + sigmoid + Sinkhorn -> gates[tok][32] ----------------
// 512 threads = 8 waves; wave w owns K-slice [w*1024, (w+1)*1024) for a 16-token tile.
__global__ __launch_bounds__(512, 1)
void logits_gates(const float* __restrict__ x,
                  const float* __restrict__ wnorm,
                  const unsigned short* __restrict__ phiT,
                  const float* __restrict__ b_pre, const float* __restrict__ b_post,
                  const float* __restrict__ b_res,
                  const float* __restrict__ a_pre, const float* __restrict__ a_post,
                  const float* __restrict__ a_res,
                  const int* __restrict__ aidx_arr,
                  float* __restrict__ gates) {
  __shared__ unsigned short xs[8][16 * 264];   // per-wave bf16 tile [16 tok][256 feat], row pad 264
  __shared__ float logits_s[8][16][32];
  __shared__ float ssq_s[8][16];

  const int tid = threadIdx.x;
  const int wave = tid >> 6, lane = tid & 63;
  const int tok0 = blockIdx.x * 16;
  const int aidx = aidx_arr[tok0 >> 10];
  const int kbase = wave * 1024;

  const float* xbase = x + (size_t)tok0 * NCF + kbase + lane * 4;
  const float* wbase = wnorm + (size_t)aidx * NCF + kbase + lane * 4;
  const unsigned short* pBbase =
      phiT + ((size_t)aidx * 32 + (lane & 15)) * NCF + kbase + (lane >> 4) * 8;

  f32x4 acc0 = {0.f, 0.f, 0.f, 0.f};
  f32x4 acc1 = {0.f, 0.f, 0.f, 0.f};
  float ssq[16];
  #pragma unroll
  for (int r = 0; r < 16; ++r) ssq[r] = 0.f;

  float4 xr[16];
  #pragma unroll
  for (int r = 0; r < 16; ++r) xr[r] = *(const float4*)(xbase + (size_t)r * NCF);

  for (int t = 0; t < 4; ++t) {
    const float4 wv = *(const float4*)(wbase + t * 256);
    // stage: ssq + bf16(w*x) -> LDS (wave-private, no barrier needed)
    #pragma unroll
    for (int r = 0; r < 16; ++r) {
      const float4 xv = xr[r];
      ssq[r] += xv.x * xv.x + xv.y * xv.y + xv.z * xv.z + xv.w * xv.w;
      ushort4 u = make_ushort4(f2bf(xv.x * wv.x), f2bf(xv.y * wv.y),
                               f2bf(xv.z * wv.z), f2bf(xv.w * wv.w));
      *(ushort4*)&xs[wave][r * 264 + lane * 4] = u;
    }
    if (t < 3) {
      #pragma unroll
      for (int r = 0; r < 16; ++r)
        xr[r] = *(const float4*)(xbase + (size_t)r * NCF + (t + 1) * 256);
    }
    const unsigned short* pB = pBbase + t * 256;
    #pragma unroll
    for (int s = 0; s < 8; ++s) {
      bf16x8 a = *(const bf16x8*)&xs[wave][(lane & 15) * 264 + s * 32 + (lane >> 4) * 8];
      bf16x8 b0 = *(const bf16x8*)(pB + s * 32);
      bf16x8 b1 = *(const bf16x8*)(pB + 16 * NCF + s * 32);
      acc0 = __builtin_amdgcn_mfma_f32_16x16x32_bf16(a, b0, acc0, 0, 0, 0);
      acc1 = __builtin_amdgcn_mfma_f32_16x16x32_bf16(a, b1, acc1, 0, 0, 0);
    }
  }

  // ssq reduce across 64 lanes
  #pragma unroll
  for (int r = 0; r < 16; ++r) {
    float v = ssq[r];
    #pragma unroll
    for (int m = 1; m <= 32; m <<= 1) v += __shfl_xor(v, m, 64);
    if (lane == 0) ssq_s[wave][r] = v;
  }
  // C frags -> LDS: D[m=tok][n=col], m=(lane>>4)*4+i, n=lane&15
  #pragma unroll
  for (int i = 0; i < 4; ++i) {
    logits_s[wave][(lane >> 4) * 4 + i][lane & 15] = acc0[i];
    logits_s[wave][(lane >> 4) * 4 + i][16 + (lane & 15)] = acc1[i];
  }
  __syncthreads();

  if (tid < 256) {
    // per-thread: tok = tid>>4 (0..15), cl = tid&15
    const int tok = tid >> 4, cl = tid & 15;
    float L0 = 0.f, L16 = 0.f, ssqt = 0.f;
    #pragma unroll
    for (int w = 0; w < 8; ++w) {
      L0 += logits_s[w][tok][cl];
      L16 += logits_s[w][tok][16 + cl];
      ssqt += ssq_s[w][tok];
    }
    const float invr = rsqrtf(ssqt * (1.f / NCF) + EPS);

    float* g = gates + (size_t)(tok0 + tok) * 32;
    if (cl < 4) {
      const float zp = a_pre[aidx] * L0 * invr + b_pre[(size_t)aidx * 4 + cl];
      g[cl] = 1.f / (1.f + __expf(-zp));
    } else if (cl < 8) {
      const float zq = a_post[aidx] * L0 * invr + b_post[(size_t)aidx * 4 + (cl - 4)];
      g[cl] = 2.f / (1.f + __expf(-zq));
    }
    // gather res logits: res[cl] = col 8+cl
    const float resv = __shfl_xor((cl & 8) ? L0 : L16, 8, 64);
    const float tl = a_res[aidx] * resv * invr + b_res[(size_t)aidx * 16 + cl];
    float m = __expf(tl);
    #pragma unroll
    for (int it = 0; it < 20; ++it) {
      float rs = m;
      rs += __shfl_xor(rs, 1, 64);
      rs += __shfl_xor(rs, 2, 64);
      m *= __builtin_amdgcn_rcpf(rs);
      float cs = m;
      cs += __shfl_xor(cs, 4, 64);
      cs += __shfl_xor(cs, 8, 64);
      m *= __builtin_amdgcn_rcpf(cs);
    }
    g[8 + cl] = m;
  }
}

// ---------------- K3: streaming output pass ----------------
__global__ __launch_bounds__(256)
void out_pass(const float* __restrict__ x, const float* __restrict__ outp,
              const float* __restrict__ gates,
              float* __restrict__ agg, float* __restrict__ big) {
  const int tok = blockIdx.x;
  const int tid = threadIdx.x;
  const float* g = gates + (size_t)tok * 32;
  float hp[4], hq[4], M[16];
  #pragma unroll
  for (int i = 0; i < 4; ++i) { hp[i] = g[i]; hq[i] = g[4 + i]; }
  #pragma unroll
  for (int i = 0; i < 16; ++i) M[i] = g[8 + i];

  const float* xrow = x + (size_t)tok * NCF;
  const float* orow = outp + (size_t)tok * CCH;
  float* arow = agg + (size_t)tok * CCH;
  float* brow = big + (size_t)tok * NCF;

  #pragma unroll
  for (int rep = 0; rep < 2; ++rep) {
    const int c = rep * 1024 + tid * 4;
    float4 xv[4];
    #pragma unroll
    for (int j = 0; j < 4; ++j) xv[j] = *(const float4*)(xrow + j * CCH + c);
    const float4 ov = *(const float4*)(orow + c);

    f32x4 ag;
    ag.x = hp[0]*xv[0].x + hp[1]*xv[1].x + hp[2]*xv[2].x + hp[3]*xv[3].x;
    ag.y = hp[0]*xv[0].y + hp[1]*xv[1].y + hp[2]*xv[2].y + hp[3]*xv[3].y;
    ag.z = hp[0]*xv[0].z + hp[1]*xv[1].z + hp[2]*xv[2].z + hp[3]*xv[3].z;
    ag.w = hp[0]*xv[0].w + hp[1]*xv[1].w + hp[2]*xv[2].w + hp[3]*xv[3].w;
    __builtin_nontemporal_store(ag, (f32x4*)(arow + c));

    #pragma unroll
    for (int i = 0; i < 4; ++i) {
      const float m0 = M[i*4+0], m1 = M[i*4+1], m2 = M[i*4+2], m3 = M[i*4+3];
      f32x4 o;
      o.x = m0*xv[0].x + m1*xv[1].x + m2*xv[2].x + m3*xv[3].x + hq[i]*ov.x;
      o.y = m0*xv[0].y + m1*xv[1].y + m2*xv[2].y + m3*xv[3].y + hq[i]*ov.y;
      o.z = m0*xv[0].z + m1*xv[1].z + m2*xv[2].z + m3*xv[3].z + hq[i]*ov.z;
      o.w = m0*xv[0].w + m1*xv[1].w + m2*xv[2].w + m3*xv[3].w + hq[i]*ov.w;
      __builtin_nontemporal_store(o, (f32x4*)(brow + i * CCH + c));
    }
  }
}

// ---------------- fallback: round-1 fused kernel (used if ws too small) ----------------
__global__ __launch_bounds__(256, 4)
void lora_fused(const float* __restrict__ x, const float* __restrict__ outp,
                const float* __restrict__ wnorm, const float* __restrict__ phi_pre,
                const float* __restrict__ phi_post, const float* __restrict__ phi_res,
                const float* __restrict__ b_pre, const float* __restrict__ b_post,
                const float* __restrict__ b_res, const float* __restrict__ a_pre,
                const float* __restrict__ a_post, const float* __restrict__ a_res,
                const int* __restrict__ aidx_arr, float* __restrict__ agg_out,
                float* __restrict__ big_out) {
  __shared__ unsigned short xsb[2][NCF];
  __shared__ float scratch[4][52];
  __shared__ float red[52];
  __shared__ float Hpre[2][4], Hpost[2][4], Msm[2][16];
  const int tid = threadIdx.x;
  const int tok0 = blockIdx.x * 2;
  const int aidx = aidx_arr[tok0 >> 10];
  const float* xr0 = x + (size_t)tok0 * NCF;
  const float* xr1 = xr0 + NCF;
  const float* wr = wnorm + (size_t)aidx * NCF;
  const float* pp = phi_pre + (size_t)aidx * NCF * 4;
  const float* pq = phi_post + (size_t)aidx * NCF * 4;
  const float* pr = phi_res + (size_t)aidx * NCF * 16;
  float acc[50];
  #pragma unroll
  for (int i = 0; i < 50; ++i) acc[i] = 0.f;
  for (int k = 0; k < 8; ++k) {
    const int f0 = (k * 256 + tid) * 4;
    const float4 w4 = *(const float4*)(wr + f0);
    const float4 xa = *(const float4*)(xr0 + f0);
    const float4 xb = *(const float4*)(xr1 + f0);
    acc[0] += xa.x*xa.x + xa.y*xa.y + xa.z*xa.z + xa.w*xa.w;
    acc[25] += xb.x*xb.x + xb.y*xb.y + xb.z*xb.z + xb.w*xb.w;
    float xw0[4] = { xa.x*w4.x, xa.y*w4.y, xa.z*w4.z, xa.w*w4.w };
    float xw1[4] = { xb.x*w4.x, xb.y*w4.y, xb.z*w4.z, xb.w*w4.w };
    *(ushort4*)&xsb[0][f0] = make_ushort4(f2bf(xa.x), f2bf(xa.y), f2bf(xa.z), f2bf(xa.w));
    *(ushort4*)&xsb[1][f0] = make_ushort4(f2bf(xb.x), f2bf(xb.y), f2bf(xb.z), f2bf(xb.w));
    #pragma unroll
    for (int d = 0; d < 4; ++d) {
      const int f = f0 + d;
      const float a0 = xw0[d], a1 = xw1[d];
      float col[24];
      const float4 P = *(const float4*)(pp + ((size_t)f << 2));
      const float4 Q = *(const float4*)(pq + ((size_t)f << 2));
      const float4 R0 = *(const float4*)(pr + ((size_t)f << 4));
      const float4 R1 = *(const float4*)(pr + ((size_t)f << 4) + 4);
      const float4 R2 = *(const float4*)(pr + ((size_t)f << 4) + 8);
      const float4 R3 = *(const float4*)(pr + ((size_t)f << 4) + 12);
      col[0]=P.x; col[1]=P.y; col[2]=P.z; col[3]=P.w;
      col[4]=Q.x; col[5]=Q.y; col[6]=Q.z; col[7]=Q.w;
      col[8]=R0.x; col[9]=R0.y; col[10]=R0.z; col[11]=R0.w;
      col[12]=R1.x; col[13]=R1.y; col[14]=R1.z; col[15]=R1.w;
      col[16]=R2.x; col[17]=R2.y; col[18]=R2.z; col[19]=R2.w;
      col[20]=R3.x; col[21]=R3.y; col[22]=R3.z; col[23]=R3.w;
      #pragma unroll
      for (int c = 0; c < 24; ++c) { acc[1 + c] += a0 * col[c]; acc[26 + c] += a1 * col[c]; }
    }
  }
  #pragma unroll
  for (int m = 1; m <= 32; m <<= 1) {
    #pragma unroll
    for (int v = 0; v < 50; ++v) acc[v] += __shfl_xor(acc[v], m, 64);
  }
  const int wave = tid >> 6, lane = tid & 63;
  if (lane == 0) {
    #pragma unroll
    for (int v = 0; v < 50; ++v) scratch[wave][v] = acc[v];
  }
  __syncthreads();
  if (tid < 50) red[tid] = scratch[0][tid] + scratch[1][tid] + scratch[2][tid] + scratch[3][tid];
  __syncthreads();
  if (tid < 32) {
    const int t = tid >> 4, l = tid & 15;
    const float invr = rsqrtf(red[t * 25] * (1.f / NCF) + EPS);
    const float tl = a_res[aidx] * red[t * 25 + 1 + 8 + l] * invr + b_res[(size_t)aidx * 16 + l];
    float m = __expf(tl);
    #pragma unroll
    for (int it = 0; it < 20; ++it) {
      float rs = m; rs += __shfl_xor(rs, 1, 64); rs += __shfl_xor(rs, 2, 64);
      m *= __builtin_amdgcn_rcpf(rs);
      float cs = m; cs += __shfl_xor(cs, 4, 64); cs += __shfl_xor(cs, 8, 64);
      m *= __builtin_amdgcn_rcpf(cs);
    }
    Msm[t][l] = m;
  } else if (tid < 40) {
    const int q = tid - 32, t = q >> 2, n = q & 3;
    const float invr = rsqrtf(red[t * 25] * (1.f / NCF) + EPS);
    const float zp = a_pre[aidx] * red[t * 25 + 1 + n] * invr + b_pre[(size_t)aidx * 4 + n];
    const float zq = a_post[aidx] * red[t * 25 + 1 + 4 + n] * invr + b_post[(size_t)aidx * 4 + n];
    Hpre[t][n] = 1.f / (1.f + __expf(-zp));
    Hpost[t][n] = 2.f / (1.f + __expf(-zq));
  }
  __syncthreads();
  #pragma unroll
  for (int t = 0; t < 2; ++t) {
    const int tok = tok0 + t;
    const float* orow = outp + (size_t)tok * CCH;
    float* arow = agg_out + (size_t)tok * CCH;
    float* brow = big_out + (size_t)tok * 4 * CCH;
    const float hp0 = Hpre[t][0], hp1 = Hpre[t][1], hp2 = Hpre[t][2], hp3 = Hpre[t][3];
    float Mr[16];
    #pragma unroll
    for (int i = 0; i < 16; ++i) Mr[i] = Msm[t][i];
    const float hq[4] = { Hpost[t][0], Hpost[t][1], Hpost[t][2], Hpost[t][3] };
    #pragma unroll
    for (int w = 0; w < 2; ++w) {
      const int c0 = (w * 256 + tid) * 4;
      float4 xv[4];
      #pragma unroll
      for (int n = 0; n < 4; ++n) {
        const ushort4 u = *(const ushort4*)&xsb[t][n * CCH + c0];
        xv[n] = make_float4(bf2f(u.x), bf2f(u.y), bf2f(u.z), bf2f(u.w));
      }
      const float4 ov = *(const float4*)(orow + c0);
      float4 ag;
      ag.x = hp0*xv[0].x + hp1*xv[1].x + hp2*xv[2].x + hp3*xv[3].x;
      ag.y = hp0*xv[0].y + hp1*xv[1].y + hp2*xv[2].y + hp3*xv[3].y;
      ag.z = hp0*xv[0].z + hp1*xv[1].z + hp2*xv[2].z + hp3*xv[3].z;
      ag.w = hp0*xv[0].w + hp1*xv[1].w + hp2*xv[2].w + hp3*xv[3].w;
      *(float4*)(arow + c0) = ag;
      #pragma unroll
      for (int i = 0; i < 4; ++i) {
        const float m0 = Mr[i*4+0], m1 = Mr[i*4+1], m2 = Mr[i*4+2], m3 = Mr[i*4+3];
        float4 o;
        o.x = m0*xv[0].x + m1*xv[1].x + m2*xv[2].x + m3*xv[3].x + hq[i]*ov.x;
        o.y = m0*xv[0].y + m1*xv[1].y + m2*xv[2].y + m3*xv[3].y + hq[i]*ov.y;
        o.z = m0*xv[0].z + m1*xv[1].z + m2*xv[2].z + m3*xv[3].z + hq[i]*ov.z;
        o.w = m0*xv[0].w + m1*xv[1].w + m2*xv[2].w + m3*xv[3].w + hq[i]*ov.w;
        *(float4*)(brow + (size_t)i * CCH + c0) = o;
      }
    }
  }
}

extern "C" void kernel_launch(void* const* d_in, const int* in_sizes, int n_in,
                              void* d_out, int out_size, void* d_ws, size_t ws_size,
                              hipStream_t stream) {
  const float* x     = (const float*)d_in[0];
  const float* outp  = (const float*)d_in[1];
  const float* wnorm = (const float*)d_in[2];
  const float* ppre  = (const float*)d_in[3];
  const float* ppost = (const float*)d_in[4];
  const float* pres  = (const float*)d_in[5];
  const float* bpre  = (const float*)d_in[6];
  const float* bpost = (const float*)d_in[7];
  const float* bres  = (const float*)d_in[8];
  const float* apre  = (const float*)d_in[9];
  const float* apost = (const float*)d_in[10];
  const float* ares  = (const float*)d_in[11];
  const int*   aidx  = (const int*)d_in[12];

  float* agg = (float*)d_out;
  float* big = (float*)d_out + (size_t)TOKS * CCH;

  if (ws_size >= WS_NEED) {
    unsigned short* phiT = (unsigned short*)d_ws;
    float* gates = (float*)((char*)d_ws + GATES_OFF);
    hipLaunchKernelGGL(prep_phiT, dim3(1024), dim3(256), 0, stream, ppre, ppost, pres, phiT);
    hipLaunchKernelGGL(logits_gates, dim3(256), dim3(512), 0, stream,
                       x, wnorm, phiT, bpre, bpost, bres, apre, apost, ares, aidx, gates);
    hipLaunchKernelGGL(out_pass, dim3(4096), dim3(256), 0, stream, x, outp, gates, agg, big);
  } else {
    hipLaunchKernelGGL(lora_fused, dim3(2048), dim3(256), 0, stream,
                       x, outp, wnorm, ppre, ppost, pres,
                       bpre, bpost, bres, apre, apost, ares, aidx, agg, big);
  }
}